// Round 16
// baseline (269.316 us; speedup 1.0000x reference)
//
#include <hip/hip_runtime.h>
#include <hip/hip_bf16.h>

#define N_NODES 50000
#define N_EDGES 800000
#define D_IN 128
#define D_HID 512
#define D_OUT 128
#define CAT_DIM 640   // D_IN + D_HID
#define CAPH 32       // per-half capacity (Poisson(8): P(>32) ~ 3e-11)
#define HALF 25000    // trg-phase split point

typedef __attribute__((ext_vector_type(8))) short short8;
typedef __attribute__((ext_vector_type(4))) float floatx4;

__device__ __forceinline__ unsigned short f2bf(float f) {
    unsigned u = __float_as_uint(f);
    unsigned r = u + 0x7fffu + ((u >> 16) & 1u);   // RNE
    return (unsigned short)(r >> 16);
}

// convert 8 consecutive fp32 -> 8 bf16 (same bits as a pre-cast pass)
__device__ __forceinline__ void cvt8(const float* __restrict__ src, unsigned short* o) {
    float4 v0 = *(const float4*)src;
    float4 v1 = *(const float4*)(src + 4);
    o[0] = f2bf(v0.x); o[1] = f2bf(v0.y); o[2] = f2bf(v0.z); o[3] = f2bf(v0.w);
    o[4] = f2bf(v1.x); o[5] = f2bf(v1.y); o[6] = f2bf(v1.z); o[7] = f2bf(v1.w);
}

// ================= edge binning parameters =================================

#define NBKT 196         // ceil(50000/256)
#define BKT_SHIFT 8
#define CAPB 6144        // staging capacity/bucket (mean 4082, +32 sigma)
#define P1_CHUNK 4096
#define P1_BLOCKS 196    // ceil(800000/4096)

// ================= k1: binning ∥ GEMM1 (B transposed on the fly) ∥ WT ======
// prep_w dispatch deleted: gemm1 blocks stage B straight from fp32 fcW
// (256 KB, L2-resident) with an in-register 8k x 4n transpose -- identical
// f2bf bits to the old fcwT path, same ds_write_b128 count, no fcwT buffer,
// no prep dependency. WT transpose rides as tail blocks (consumer is gemm2,
// 3 dispatches later). bucket_cnt zeroed by hipMemsetAsync.
// Binning + gemm1 geometry unchanged from R12/R13 (LDS 35840 B, 4 blocks/CU).

#define S1_G1_BLOCKS 782    // ceil(50000/64)
#define S1_WT_BLOCKS 320    // 640*128 / 256
#define S1_BLOCKS (P1_BLOCKS + S1_G1_BLOCKS + S1_WT_BLOCKS)
#define G1_PAD 8
#define SM1_BYTES (64 * (D_IN + G1_PAD) * 2 + 128 * (64 + G1_PAD) * 2)   // 35840

__global__ __launch_bounds__(256)
void sort_gemm1_kernel(const int* __restrict__ adj,
                       int* __restrict__ bucket_cnt, uint2* __restrict__ staging,
                       const float* __restrict__ X,
                       const float* __restrict__ fcW,
                       const float* __restrict__ fcb,
                       unsigned short* __restrict__ F,
                       const float* __restrict__ Wm, unsigned short* __restrict__ WT) {
    __shared__ alignas(16) char smem[SM1_BYTES];
    int b = blockIdx.x, tid = threadIdx.x;
    if (b < P1_BLOCKS) {
        uint2* les = (uint2*)smem;                     // 32 KB
        int* cnt   = (int*)(smem + P1_CHUNK * 8);      // 196 ints
        int* woff  = cnt + NBKT;
        for (int i = tid; i < NBKT; i += 256) cnt[i] = 0;
        // per-wave dtype detect: int64 iff high dwords of first 64 ids all zero
        int v = adj[2 * (tid & 63) + 1];
        int s = (__ballot(v != 0) == 0ULL) ? 2 : 1;
        __syncthreads();
        int e0 = b * P1_CHUNK;
        int ne = N_EDGES - e0; if (ne > P1_CHUNK) ne = P1_CHUNK;
        for (int j = tid; j < ne; j += 256) {
            int e = e0 + j;
            int src, trg;
            if (s == 2) { src = adj[2 * (size_t)e]; trg = adj[2 * ((size_t)N_EDGES + e)]; }
            else        { src = adj[e];             trg = adj[N_EDGES + e]; }
            les[j] = make_uint2((unsigned)src, (unsigned)trg);
            atomicAdd(&cnt[src >> BKT_SHIFT], 1);           // LDS atomic
        }
        __syncthreads();
        for (int i = tid; i < NBKT; i += 256)
            woff[i] = atomicAdd(&bucket_cnt[i], cnt[i]);    // 196 global atomics/block
        __syncthreads();
        for (int j = tid; j < ne; j += 256) {
            uint2 et = les[j];
            int bk = (int)(et.x >> BKT_SHIFT);
            int pos = atomicAdd(&woff[bk], 1);              // LDS atomic
            if (pos < CAPB) staging[(size_t)bk * CAPB + pos] = et;
        }
        return;
    }
    b -= P1_BLOCKS;
    if (b < S1_G1_BLOCKS) {
        typedef unsigned short RowA[D_IN + G1_PAD];
        typedef unsigned short RowB[64 + G1_PAD];
        RowA* As = (RowA*)smem;
        RowB* Bs = (RowB*)(smem + 64 * (D_IN + G1_PAD) * 2);
        int lane = tid & 63, w = tid >> 6;
        int bm = b * 64;
        {   // stage A once: 4 passes x (16 rows x 128 cols), fp32 -> bf16
            int r = tid >> 4;
            int c = (tid & 15) * 8;
            #pragma unroll
            for (int p = 0; p < 4; ++p) {
                int row = r + p * 16;
                int gr = bm + row;
                unsigned short o[8] = {0, 0, 0, 0, 0, 0, 0, 0};
                if (gr < N_NODES) cvt8(X + (size_t)gr * D_IN + c, o);
                *(uint4*)(&As[row][c]) = *(const uint4*)o;
            }
        }
        int wm = (w >> 1) * 32, wn = (w & 1) * 64;
        int q = lane >> 4, l16 = lane & 15;
        int nb = (tid >> 3) * 4;       // B-stage: this thread's n-base (0..124)
        int kb = (tid & 7) * 8;        //          and k-base (0..56)
        for (int nc = 0; nc < 4; ++nc) {
            floatx4 acc[2][4] = {};
            #pragma unroll
            for (int kh = 0; kh < 2; ++kh) {
                {   // transpose-stage B from fp32 fcW: Bs[n][k] = f2bf(fcW[kh*64+k][nc*128+n])
                    // 8 lanes (t, t+8, ..) read 128 contiguous B per fcW row -> full lines.
                    float4 v[8];
                    #pragma unroll
                    for (int dk = 0; dk < 8; ++dk)
                        v[dk] = *(const float4*)(fcW + (size_t)(kh * 64 + kb + dk) * D_HID
                                                 + nc * 128 + nb);
                    #pragma unroll
                    for (int dn = 0; dn < 4; ++dn) {
                        unsigned short o[8];
                        #pragma unroll
                        for (int dk = 0; dk < 8; ++dk)
                            o[dk] = f2bf(((const float*)&v[dk])[dn]);
                        *(uint4*)(&Bs[nb + dn][kb]) = *(const uint4*)o;
                    }
                }
                __syncthreads();
                #pragma unroll
                for (int ks = 0; ks < 2; ++ks) {
                    short8 af[2], bf[4];
                    #pragma unroll
                    for (int mi = 0; mi < 2; ++mi)
                        af[mi] = *(const short8*)(&As[wm + mi * 16 + l16][kh * 64 + ks * 32 + q * 8]);
                    #pragma unroll
                    for (int ni = 0; ni < 4; ++ni)
                        bf[ni] = *(const short8*)(&Bs[wn + ni * 16 + l16][ks * 32 + q * 8]);
                    #pragma unroll
                    for (int mi = 0; mi < 2; ++mi)
                        #pragma unroll
                        for (int ni = 0; ni < 4; ++ni)
                            acc[mi][ni] = __builtin_amdgcn_mfma_f32_16x16x32_bf16(af[mi], bf[ni], acc[mi][ni], 0, 0, 0);
                }
                __syncthreads();   // protect Bs before restage
            }
            #pragma unroll
            for (int mi = 0; mi < 2; ++mi)
                #pragma unroll
                for (int ni = 0; ni < 4; ++ni)
                    #pragma unroll
                    for (int r = 0; r < 4; ++r) {
                        int row = bm + wm + mi * 16 + q * 4 + r;
                        int col = nc * 128 + wn + ni * 16 + l16;
                        if (row < N_NODES) {
                            float v = fmaxf(acc[mi][ni][r] + fcb[col], 0.0f);
                            F[(size_t)row * D_HID + col] = f2bf(v);
                        }
                    }
        }
        return;
    }
    b -= S1_G1_BLOCKS;
    {   // WT transpose (consumer: gemm2, 3 dispatches later)
        int idx = b * 256 + tid;               // 640*128
        int k = idx >> 7;
        int n = idx & (D_OUT - 1);
        WT[n * CAT_DIM + k] = f2bf(Wm[idx]);
    }
}

// ================= k2: pass-2 scatter into phase-split el arrays ===========

__global__ __launch_bounds__(256)
void sort2_kernel(const int* __restrict__ bucket_cnt, const uint2* __restrict__ staging,
                  int* __restrict__ degp,
                  unsigned short* __restrict__ elLo, unsigned short* __restrict__ elHi) {
    __shared__ int lo[256], hi[256];
    int bk = blockIdx.x, tid = threadIdx.x;
    lo[tid] = 0; hi[tid] = 0;
    __syncthreads();
    int n = bucket_cnt[bk]; if (n > CAPB) n = CAPB;
    int base = bk << BKT_SHIFT;
    const uint2* st = staging + (size_t)bk * CAPB;
    for (int i = tid; i < n; i += 256) {
        uint2 et = st[i];
        int r = (int)et.x - base;
        int t = (int)et.y;
        if (t < HALF) {
            int p = atomicAdd(&lo[r], 1);
            if (p < CAPH) elLo[(size_t)(base + r) * CAPH + p] = (unsigned short)t;
        } else {
            int p = atomicAdd(&hi[r], 1);
            if (p < CAPH) elHi[(size_t)(base + r) * CAPH + p] = (unsigned short)t;
        }
    }
    __syncthreads();
    int src = base + tid;
    if (src < N_NODES) degp[src] = lo[tid] | (hi[tid] << 16);
}

// ================= aggregate: phase x slice x XCD (R13 EXACT) ==============
// R13 = 52.3 us/phase is the measured optimum. R14 (nt on el) and R15 (nt on
// agg store) both regressed despite lower FETCH: past ~90 MB/phase the loop
// is service-latency-bound and L2/L1 retention of every access wins. All
// loads/stores cached, plain. Do not touch.

__device__ __forceinline__ void fmax_bf16x8(float* acc, const uint4& p) {
    const unsigned* a = (const unsigned*)&p;
    #pragma unroll
    for (int j = 0; j < 4; ++j) {
        unsigned u = a[j];
        acc[2 * j]     = fmaxf(acc[2 * j],     __uint_as_float(u << 16));
        acc[2 * j + 1] = fmaxf(acc[2 * j + 1], __uint_as_float(u & 0xffff0000u));
    }
}

#define AGG_CHUNKS 1563   // ceil(50000/32)

template<int H>
__global__ __launch_bounds__(256)
void aggregate_phase(const unsigned short* __restrict__ F,
                     const int* __restrict__ degp,
                     const unsigned short* __restrict__ el,
                     unsigned short* __restrict__ agg) {
    int tid = threadIdx.x;
    int s = blockIdx.x & 7;            // column slice -> XCD (default %8 map)
    int chunk = blockIdx.x >> 3;
    int n = chunk * 32 + (tid >> 3);   // node owned by this 8-lane group
    int ch = tid & 7;                  // 16B chunk within the 128B slice
    if (n >= N_NODES) return;
    int dp = degp[n];
    int d = H ? (dp >> 16) : (dp & 0xffff);
    d = d < CAPH ? d : CAPH;
    const unsigned short* Fs = F + s * 64 + ch * 8;
    const unsigned short* ep = el + (size_t)n * CAPH;
    unsigned short* ap = agg + (size_t)n * D_HID + s * 64 + ch * 8;
    float acc[8];
    if (H) {   // seed from phase-0 result (bf16 -> f32, exact)
        uint4 a0 = *(const uint4*)ap;
        const unsigned* au = (const unsigned*)&a0;
        #pragma unroll
        for (int j = 0; j < 4; ++j) {
            acc[2 * j]     = __uint_as_float(au[j] << 16);
            acc[2 * j + 1] = __uint_as_float(au[j] & 0xffff0000u);
        }
    } else {
        #pragma unroll
        for (int j = 0; j < 8; ++j) acc[j] = 0.0f;
    }
    #pragma unroll 2
    for (int i = 0; i < d; ++i) {
        int t = ep[i];
        uint4 p = *(const uint4*)(Fs + (size_t)t * D_HID);
        fmax_bf16x8(acc, p);
    }
    unsigned o[4];
    #pragma unroll
    for (int j = 0; j < 4; ++j) {
        unsigned lov = __float_as_uint(acc[2 * j]) >> 16;      // exact: maxima of bf16
        unsigned hiv = __float_as_uint(acc[2 * j + 1]) & 0xffff0000u;
        o[j] = lov | hiv;
    }
    *(uint4*)ap = *(uint4*)o;
}

// ================= GEMM2: A = [X fp32 | agg bf16], B = WT ==================
// BM=64, BN=128 (full D_OUT), BK=64, 10 K-steps. LDS 27648 B.

#define GPAD 8
#define GEMM_MT 782   // ceil(50000/64)

__global__ __launch_bounds__(256)
void gemm2_kernel(const float* __restrict__ X,
                  const unsigned short* __restrict__ agg,
                  const unsigned short* __restrict__ WT,
                  float* __restrict__ out) {
    __shared__ unsigned short As[64][64 + GPAD];
    __shared__ unsigned short Bs[128][64 + GPAD];
    int tid = threadIdx.x;
    int lane = tid & 63, w = tid >> 6;
    int wm = (w >> 1) * 32, wn = (w & 1) * 64;
    int q = lane >> 4, l16 = lane & 15;
    int bm = blockIdx.x * 64;
    floatx4 acc[2][4] = {};
    int ra = tid >> 2;            // A row 0..63
    int ca = (tid & 3) * 8;       // A col base; passes +0,+32
    int rb = tid >> 1;            // B row 0..127
    int cb = (tid & 1) * 8;       // B col base; passes +0,+16,+32,+48

    for (int k0 = 0; k0 < CAT_DIM; k0 += 64) {
        {
            int gr = bm + ra;
            #pragma unroll
            for (int p = 0; p < 2; ++p) {
                int col = k0 + ca + p * 32;
                unsigned short o[8] = {0, 0, 0, 0, 0, 0, 0, 0};
                if (gr < N_NODES) {
                    if (col < D_IN) cvt8(X + (size_t)gr * D_IN + col, o);
                    else *(uint4*)o = *(const uint4*)(agg + (size_t)gr * D_HID + (col - D_IN));
                }
                *(uint4*)(&As[ra][ca + p * 32]) = *(const uint4*)o;
            }
        }
        {
            const unsigned short* bp = WT + (size_t)rb * CAT_DIM + k0 + cb;
            #pragma unroll
            for (int p = 0; p < 4; ++p)
                *(uint4*)(&Bs[rb][cb + p * 16]) = *(const uint4*)(bp + p * 16);
        }
        __syncthreads();
        #pragma unroll
        for (int ks = 0; ks < 2; ++ks) {
            short8 af[2], bf[4];
            #pragma unroll
            for (int mi = 0; mi < 2; ++mi)
                af[mi] = *(const short8*)(&As[wm + mi * 16 + l16][ks * 32 + q * 8]);
            #pragma unroll
            for (int ni = 0; ni < 4; ++ni)
                bf[ni] = *(const short8*)(&Bs[wn + ni * 16 + l16][ks * 32 + q * 8]);
            #pragma unroll
            for (int mi = 0; mi < 2; ++mi)
                #pragma unroll
                for (int ni = 0; ni < 4; ++ni)
                    acc[mi][ni] = __builtin_amdgcn_mfma_f32_16x16x32_bf16(af[mi], bf[ni], acc[mi][ni], 0, 0, 0);
        }
        __syncthreads();
    }

    #pragma unroll
    for (int mi = 0; mi < 2; ++mi)
        #pragma unroll
        for (int ni = 0; ni < 4; ++ni)
            #pragma unroll
            for (int r = 0; r < 4; ++r) {
                int row = bm + wm + mi * 16 + q * 4 + r;
                int col = wn + ni * 16 + l16;
                if (row < N_NODES)
                    out[(size_t)row * D_OUT + col] = acc[mi][ni][r];
            }
}

// ================= host launch =============================================

extern "C" void kernel_launch(void* const* d_in, const int* in_sizes, int n_in,
                              void* d_out, int out_size, void* d_ws, size_t ws_size,
                              hipStream_t stream) {
    const float* X    = (const float*)d_in[0];
    const float* fc_w = (const float*)d_in[1];
    const float* fc_b = (const float*)d_in[2];
    const float* Wm   = (const float*)d_in[3];
    const int*   adj  = (const int*)d_in[4];
    float* outp = (float*)d_out;

    char* ws = (char*)d_ws;
    size_t off = 0;
    auto alloc = [&](size_t bytes) -> void* {
        void* p = ws + off;
        off = (off + bytes + 255) & ~(size_t)255;
        return p;
    };
    unsigned short* agg    = (unsigned short*)alloc((size_t)N_NODES * D_HID * 2);
    unsigned short* F      = (unsigned short*)alloc((size_t)N_NODES * D_HID * 2);
    unsigned short* WT     = (unsigned short*)alloc((size_t)D_OUT * CAT_DIM * 2);
    int* degp      = (int*)alloc((size_t)N_NODES * 4);
    unsigned short* elLo = (unsigned short*)alloc((size_t)N_NODES * CAPH * 2);
    unsigned short* elHi = (unsigned short*)alloc((size_t)N_NODES * CAPH * 2);
    int* bucket_cnt = (int*)alloc((size_t)NBKT * 4);
    uint2* staging  = (uint2*)alloc((size_t)NBKT * CAPB * 8);

    hipMemsetAsync(bucket_cnt, 0, (size_t)NBKT * 4, stream);
    sort_gemm1_kernel<<<S1_BLOCKS, 256, 0, stream>>>(adj, bucket_cnt, staging,
                                                     X, fc_w, fc_b, F, Wm, WT);
    sort2_kernel<<<NBKT, 256, 0, stream>>>(bucket_cnt, staging, degp, elLo, elHi);
    aggregate_phase<0><<<AGG_CHUNKS * 8, 256, 0, stream>>>(F, degp, elLo, agg);
    aggregate_phase<1><<<AGG_CHUNKS * 8, 256, 0, stream>>>(F, degp, elHi, agg);
    gemm2_kernel<<<GEMM_MT, 256, 0, stream>>>(X, agg, WT, outp);
}

// Round 17
// 249.356 us; speedup vs baseline: 1.0800x; 1.0800x over previous
//
#include <hip/hip_runtime.h>
#include <hip/hip_bf16.h>

#define N_NODES 50000
#define N_EDGES 800000
#define D_IN 128
#define D_HID 512
#define D_OUT 128
#define CAT_DIM 640   // D_IN + D_HID
#define CAPH 32       // per-half capacity (Poisson(8): P(>32) ~ 3e-11)
#define HALF 25000    // trg-phase split point

typedef __attribute__((ext_vector_type(8))) short short8;
typedef __attribute__((ext_vector_type(4))) float floatx4;

__device__ __forceinline__ unsigned short f2bf(float f) {
    unsigned u = __float_as_uint(f);
    unsigned r = u + 0x7fffu + ((u >> 16) & 1u);   // RNE
    return (unsigned short)(r >> 16);
}

// convert 8 consecutive fp32 -> 8 bf16 (same bits as a pre-cast pass)
__device__ __forceinline__ void cvt8(const float* __restrict__ src, unsigned short* o) {
    float4 v0 = *(const float4*)src;
    float4 v1 = *(const float4*)(src + 4);
    o[0] = f2bf(v0.x); o[1] = f2bf(v0.y); o[2] = f2bf(v0.z); o[3] = f2bf(v0.w);
    o[4] = f2bf(v1.x); o[5] = f2bf(v1.y); o[6] = f2bf(v1.z); o[7] = f2bf(v1.w);
}

// ================= edge binning parameters =================================

#define NBKT 196         // ceil(50000/256)
#define BKT_SHIFT 8
#define CAPB 6144        // staging capacity/bucket (mean 4082, +32 sigma)
#define P1_CHUNK 4096
#define P1_BLOCKS 196    // ceil(800000/4096)

// ================= k0: weight transposes + bucket_cnt zero (R13 exact) =====
// R16 lesson: on-the-fly fp32 B-transpose doubled k1's staging bytes AND the
// WT tail blocks broke k1's single-round packing (1298 > 1024). Reverted.

#define K0_FCW_BLOCKS 256   // 128*512 / 256
#define K0_WT_BLOCKS  320   // 640*128 / 256
#define K0_BLOCKS (K0_FCW_BLOCKS + K0_WT_BLOCKS + 1)

__global__ __launch_bounds__(256)
void prep_w_kernel(const float* __restrict__ fcW, const float* __restrict__ Wm,
                   unsigned short* __restrict__ fcwT, unsigned short* __restrict__ WT,
                   int* __restrict__ bucket_cnt) {
    int b = blockIdx.x, tid = threadIdx.x;
    if (b < K0_FCW_BLOCKS) {
        int idx = b * 256 + tid;               // 128*512
        int k = idx >> 9;
        int n = idx & (D_HID - 1);
        fcwT[n * D_IN + k] = f2bf(fcW[idx]);
        return;
    }
    b -= K0_FCW_BLOCKS;
    if (b < K0_WT_BLOCKS) {
        int idx = b * 256 + tid;               // 640*128
        int k = idx >> 7;
        int n = idx & (D_OUT - 1);
        WT[n * CAT_DIM + k] = f2bf(Wm[idx]);
        return;
    }
    if (tid < NBKT) bucket_cnt[tid] = 0;
}

// ================= k1: binning ∥ GEMM1 (R13 exact + Xb emit) ===============
// R12/R13 form: LDS 35840 B -> 4 blocks/CU; grid 978 <= 1024 resident ->
// single round. NEW: gemm1 blocks already hold the bf16 X tile -- also store
// it to Xb (12.8 MB coalesced writes, k1 is not byte-bound) so gemm2 reads
// 12.8 MB bf16 instead of 25.6 MB fp32.

#define S1_G1_BLOCKS 782    // ceil(50000/64)
#define S1_BLOCKS (P1_BLOCKS + S1_G1_BLOCKS)
#define G1_PAD 8
#define SM1_BYTES (64 * (D_IN + G1_PAD) * 2 + 128 * (64 + G1_PAD) * 2)   // 35840

__global__ __launch_bounds__(256)
void sort_gemm1_kernel(const int* __restrict__ adj,
                       int* __restrict__ bucket_cnt, uint2* __restrict__ staging,
                       const float* __restrict__ X,
                       const unsigned short* __restrict__ fcwT,
                       const float* __restrict__ fcb,
                       unsigned short* __restrict__ F,
                       unsigned short* __restrict__ Xb) {
    __shared__ alignas(16) char smem[SM1_BYTES];
    int b = blockIdx.x, tid = threadIdx.x;
    if (b < P1_BLOCKS) {
        uint2* les = (uint2*)smem;                     // 32 KB
        int* cnt   = (int*)(smem + P1_CHUNK * 8);      // 196 ints
        int* woff  = cnt + NBKT;
        for (int i = tid; i < NBKT; i += 256) cnt[i] = 0;
        // per-wave dtype detect: int64 iff high dwords of first 64 ids all zero
        int v = adj[2 * (tid & 63) + 1];
        int s = (__ballot(v != 0) == 0ULL) ? 2 : 1;
        __syncthreads();
        int e0 = b * P1_CHUNK;
        int ne = N_EDGES - e0; if (ne > P1_CHUNK) ne = P1_CHUNK;
        for (int j = tid; j < ne; j += 256) {
            int e = e0 + j;
            int src, trg;
            if (s == 2) { src = adj[2 * (size_t)e]; trg = adj[2 * ((size_t)N_EDGES + e)]; }
            else        { src = adj[e];             trg = adj[N_EDGES + e]; }
            les[j] = make_uint2((unsigned)src, (unsigned)trg);
            atomicAdd(&cnt[src >> BKT_SHIFT], 1);           // LDS atomic
        }
        __syncthreads();
        for (int i = tid; i < NBKT; i += 256)
            woff[i] = atomicAdd(&bucket_cnt[i], cnt[i]);    // 196 global atomics/block
        __syncthreads();
        for (int j = tid; j < ne; j += 256) {
            uint2 et = les[j];
            int bk = (int)(et.x >> BKT_SHIFT);
            int pos = atomicAdd(&woff[bk], 1);              // LDS atomic
            if (pos < CAPB) staging[(size_t)bk * CAPB + pos] = et;
        }
        return;
    }
    b -= P1_BLOCKS;
    {
        typedef unsigned short RowA[D_IN + G1_PAD];
        typedef unsigned short RowB[64 + G1_PAD];
        RowA* As = (RowA*)smem;
        RowB* Bs = (RowB*)(smem + 64 * (D_IN + G1_PAD) * 2);
        int lane = tid & 63, w = tid >> 6;
        int bm = b * 64;
        {   // stage A once: 4 passes x (16 rows x 128 cols), fp32 -> bf16; emit Xb
            int r = tid >> 4;
            int c = (tid & 15) * 8;
            #pragma unroll
            for (int p = 0; p < 4; ++p) {
                int row = r + p * 16;
                int gr = bm + row;
                unsigned short o[8] = {0, 0, 0, 0, 0, 0, 0, 0};
                if (gr < N_NODES) {
                    cvt8(X + (size_t)gr * D_IN + c, o);
                    *(uint4*)(Xb + (size_t)gr * D_IN + c) = *(const uint4*)o;
                }
                *(uint4*)(&As[row][c]) = *(const uint4*)o;
            }
        }
        int wm = (w >> 1) * 32, wn = (w & 1) * 64;
        int q = lane >> 4, l16 = lane & 15;
        int rb = tid >> 1;            // B row 0..127
        int cb = (tid & 1) * 8;       // B col base; passes +0,+16,+32,+48
        for (int nc = 0; nc < 4; ++nc) {
            floatx4 acc[2][4] = {};
            #pragma unroll
            for (int kh = 0; kh < 2; ++kh) {
                {   // stage B: fcwT rows [nc*128, +128), cols [kh*64, +64)
                    const unsigned short* bp = fcwT + (size_t)(nc * 128 + rb) * D_IN + kh * 64 + cb;
                    #pragma unroll
                    for (int p = 0; p < 4; ++p)
                        *(uint4*)(&Bs[rb][cb + p * 16]) = *(const uint4*)(bp + p * 16);
                }
                __syncthreads();
                #pragma unroll
                for (int ks = 0; ks < 2; ++ks) {
                    short8 af[2], bf[4];
                    #pragma unroll
                    for (int mi = 0; mi < 2; ++mi)
                        af[mi] = *(const short8*)(&As[wm + mi * 16 + l16][kh * 64 + ks * 32 + q * 8]);
                    #pragma unroll
                    for (int ni = 0; ni < 4; ++ni)
                        bf[ni] = *(const short8*)(&Bs[wn + ni * 16 + l16][ks * 32 + q * 8]);
                    #pragma unroll
                    for (int mi = 0; mi < 2; ++mi)
                        #pragma unroll
                        for (int ni = 0; ni < 4; ++ni)
                            acc[mi][ni] = __builtin_amdgcn_mfma_f32_16x16x32_bf16(af[mi], bf[ni], acc[mi][ni], 0, 0, 0);
                }
                __syncthreads();   // protect Bs before restage
            }
            #pragma unroll
            for (int mi = 0; mi < 2; ++mi)
                #pragma unroll
                for (int ni = 0; ni < 4; ++ni)
                    #pragma unroll
                    for (int r = 0; r < 4; ++r) {
                        int row = bm + wm + mi * 16 + q * 4 + r;
                        int col = nc * 128 + wn + ni * 16 + l16;
                        if (row < N_NODES) {
                            float v = fmaxf(acc[mi][ni][r] + fcb[col], 0.0f);
                            F[(size_t)row * D_HID + col] = f2bf(v);
                        }
                    }
        }
    }
}

// ================= k2: pass-2 scatter into phase-split el arrays ===========

__global__ __launch_bounds__(256)
void sort2_kernel(const int* __restrict__ bucket_cnt, const uint2* __restrict__ staging,
                  int* __restrict__ degp,
                  unsigned short* __restrict__ elLo, unsigned short* __restrict__ elHi) {
    __shared__ int lo[256], hi[256];
    int bk = blockIdx.x, tid = threadIdx.x;
    lo[tid] = 0; hi[tid] = 0;
    __syncthreads();
    int n = bucket_cnt[bk]; if (n > CAPB) n = CAPB;
    int base = bk << BKT_SHIFT;
    const uint2* st = staging + (size_t)bk * CAPB;
    for (int i = tid; i < n; i += 256) {
        uint2 et = st[i];
        int r = (int)et.x - base;
        int t = (int)et.y;
        if (t < HALF) {
            int p = atomicAdd(&lo[r], 1);
            if (p < CAPH) elLo[(size_t)(base + r) * CAPH + p] = (unsigned short)t;
        } else {
            int p = atomicAdd(&hi[r], 1);
            if (p < CAPH) elHi[(size_t)(base + r) * CAPH + p] = (unsigned short)t;
        }
    }
    __syncthreads();
    int src = base + tid;
    if (src < N_NODES) degp[src] = lo[tid] | (hi[tid] << 16);
}

// ================= merged aggregate: both phases, one dispatch =============
// Split OUTPUT buffers (aggLo/aggHi) make the phases fully independent: no
// phase-1 seed read of agg (-51.2 MB from this latency-bound kernel), and
// one launch (saves a dispatch gap). blockIdx < half -> phase 0; dispatch
// order keeps per-XCD phase coherence except a ~8% mixing window (2048
// resident of 25008). Inner loop is R13-exact (cached everything -- R14/R15
// proved nt variants regress). gemm2 combines max(aggLo, aggHi).

__device__ __forceinline__ void fmax_bf16x8(float* acc, const uint4& p) {
    const unsigned* a = (const unsigned*)&p;
    #pragma unroll
    for (int j = 0; j < 4; ++j) {
        unsigned u = a[j];
        acc[2 * j]     = fmaxf(acc[2 * j],     __uint_as_float(u << 16));
        acc[2 * j + 1] = fmaxf(acc[2 * j + 1], __uint_as_float(u & 0xffff0000u));
    }
}

#define AGG_CHUNKS 1563   // ceil(50000/32)
#define AGG_PHASE_BLOCKS (AGG_CHUNKS * 8)

__global__ __launch_bounds__(256)
void aggregate_all_kernel(const unsigned short* __restrict__ F,
                          const int* __restrict__ degp,
                          const unsigned short* __restrict__ elLo,
                          const unsigned short* __restrict__ elHi,
                          unsigned short* __restrict__ aggLo,
                          unsigned short* __restrict__ aggHi) {
    int tid = threadIdx.x;
    int H = blockIdx.x >= AGG_PHASE_BLOCKS;
    int pb = blockIdx.x - H * AGG_PHASE_BLOCKS;
    int s = pb & 7;                    // column slice -> XCD (default %8 map)
    int chunk = pb >> 3;
    int n = chunk * 32 + (tid >> 3);   // node owned by this 8-lane group
    int ch = tid & 7;                  // 16B chunk within the 128B slice
    if (n >= N_NODES) return;
    int dp = degp[n];
    int d = H ? (dp >> 16) : (dp & 0xffff);
    d = d < CAPH ? d : CAPH;
    const unsigned short* el = H ? elHi : elLo;
    unsigned short* agg = H ? aggHi : aggLo;
    const unsigned short* Fs = F + s * 64 + ch * 8;
    const unsigned short* ep = el + (size_t)n * CAPH;
    float acc[8];
    #pragma unroll
    for (int j = 0; j < 8; ++j) acc[j] = 0.0f;
    #pragma unroll 2
    for (int i = 0; i < d; ++i) {
        int t = ep[i];
        uint4 p = *(const uint4*)(Fs + (size_t)t * D_HID);
        fmax_bf16x8(acc, p);
    }
    unsigned o[4];
    #pragma unroll
    for (int j = 0; j < 4; ++j) {
        unsigned lov = __float_as_uint(acc[2 * j]) >> 16;      // exact: maxima of bf16
        unsigned hiv = __float_as_uint(acc[2 * j + 1]) & 0xffff0000u;
        o[j] = lov | hiv;
    }
    *(uint4*)(agg + (size_t)n * D_HID + s * 64 + ch * 8) = *(uint4*)o;
}

// ================= GEMM2: A = [Xb bf16 | max(aggLo,aggHi)], B = WT =========
// BM=64, BN=128 (full D_OUT), BK=64, 10 K-steps. LDS 27648 B. The per-u16
// unsigned max IS the float max here: all agg values are non-negative
// post-relu bf16 (bit order = value order for non-negative IEEE).

#define GPAD 8
#define GEMM_MT 782   // ceil(50000/64)

__global__ __launch_bounds__(256)
void gemm2_kernel(const unsigned short* __restrict__ Xb,
                  const unsigned short* __restrict__ aggLo,
                  const unsigned short* __restrict__ aggHi,
                  const unsigned short* __restrict__ WT,
                  float* __restrict__ out) {
    __shared__ unsigned short As[64][64 + GPAD];
    __shared__ unsigned short Bs[128][64 + GPAD];
    int tid = threadIdx.x;
    int lane = tid & 63, w = tid >> 6;
    int wm = (w >> 1) * 32, wn = (w & 1) * 64;
    int q = lane >> 4, l16 = lane & 15;
    int bm = blockIdx.x * 64;
    floatx4 acc[2][4] = {};
    int ra = tid >> 2;            // A row 0..63
    int ca = (tid & 3) * 8;       // A col base; passes +0,+32
    int rb = tid >> 1;            // B row 0..127
    int cb = (tid & 1) * 8;       // B col base; passes +0,+16,+32,+48

    for (int k0 = 0; k0 < CAT_DIM; k0 += 64) {
        {
            int gr = bm + ra;
            #pragma unroll
            for (int p = 0; p < 2; ++p) {
                int col = k0 + ca + p * 32;
                unsigned short o[8] = {0, 0, 0, 0, 0, 0, 0, 0};
                if (gr < N_NODES) {
                    if (col < D_IN) {
                        *(uint4*)o = *(const uint4*)(Xb + (size_t)gr * D_IN + col);
                    } else {
                        uint4 vl = *(const uint4*)(aggLo + (size_t)gr * D_HID + (col - D_IN));
                        uint4 vh = *(const uint4*)(aggHi + (size_t)gr * D_HID + (col - D_IN));
                        const unsigned short* pl = (const unsigned short*)&vl;
                        const unsigned short* ph = (const unsigned short*)&vh;
                        #pragma unroll
                        for (int j = 0; j < 8; ++j)
                            o[j] = pl[j] > ph[j] ? pl[j] : ph[j];   // exact fmax (non-neg bf16)
                    }
                }
                *(uint4*)(&As[ra][ca + p * 32]) = *(const uint4*)o;
            }
        }
        {
            const unsigned short* bp = WT + (size_t)rb * CAT_DIM + k0 + cb;
            #pragma unroll
            for (int p = 0; p < 4; ++p)
                *(uint4*)(&Bs[rb][cb + p * 16]) = *(const uint4*)(bp + p * 16);
        }
        __syncthreads();
        #pragma unroll
        for (int ks = 0; ks < 2; ++ks) {
            short8 af[2], bf[4];
            #pragma unroll
            for (int mi = 0; mi < 2; ++mi)
                af[mi] = *(const short8*)(&As[wm + mi * 16 + l16][ks * 32 + q * 8]);
            #pragma unroll
            for (int ni = 0; ni < 4; ++ni)
                bf[ni] = *(const short8*)(&Bs[wn + ni * 16 + l16][ks * 32 + q * 8]);
            #pragma unroll
            for (int mi = 0; mi < 2; ++mi)
                #pragma unroll
                for (int ni = 0; ni < 4; ++ni)
                    acc[mi][ni] = __builtin_amdgcn_mfma_f32_16x16x32_bf16(af[mi], bf[ni], acc[mi][ni], 0, 0, 0);
        }
        __syncthreads();
    }

    #pragma unroll
    for (int mi = 0; mi < 2; ++mi)
        #pragma unroll
        for (int ni = 0; ni < 4; ++ni)
            #pragma unroll
            for (int r = 0; r < 4; ++r) {
                int row = bm + wm + mi * 16 + q * 4 + r;
                int col = wn + ni * 16 + l16;
                if (row < N_NODES)
                    out[(size_t)row * D_OUT + col] = acc[mi][ni][r];
            }
}

// ================= host launch =============================================

extern "C" void kernel_launch(void* const* d_in, const int* in_sizes, int n_in,
                              void* d_out, int out_size, void* d_ws, size_t ws_size,
                              hipStream_t stream) {
    const float* X    = (const float*)d_in[0];
    const float* fc_w = (const float*)d_in[1];
    const float* fc_b = (const float*)d_in[2];
    const float* Wm   = (const float*)d_in[3];
    const int*   adj  = (const int*)d_in[4];
    float* outp = (float*)d_out;

    char* ws = (char*)d_ws;
    size_t off = 0;
    auto alloc = [&](size_t bytes) -> void* {
        void* p = ws + off;
        off = (off + bytes + 255) & ~(size_t)255;
        return p;
    };
    unsigned short* aggLo  = (unsigned short*)alloc((size_t)N_NODES * D_HID * 2);
    unsigned short* aggHi  = (unsigned short*)alloc((size_t)N_NODES * D_HID * 2);
    unsigned short* F      = (unsigned short*)alloc((size_t)N_NODES * D_HID * 2);
    unsigned short* Xb     = (unsigned short*)alloc((size_t)N_NODES * D_IN * 2);
    unsigned short* fcwT   = (unsigned short*)alloc((size_t)D_HID * D_IN * 2);
    unsigned short* WT     = (unsigned short*)alloc((size_t)D_OUT * CAT_DIM * 2);
    int* degp      = (int*)alloc((size_t)N_NODES * 4);
    unsigned short* elLo = (unsigned short*)alloc((size_t)N_NODES * CAPH * 2);
    unsigned short* elHi = (unsigned short*)alloc((size_t)N_NODES * CAPH * 2);
    int* bucket_cnt = (int*)alloc((size_t)NBKT * 4);
    uint2* staging  = (uint2*)alloc((size_t)NBKT * CAPB * 8);

    prep_w_kernel<<<K0_BLOCKS, 256, 0, stream>>>(fc_w, Wm, fcwT, WT, bucket_cnt);
    sort_gemm1_kernel<<<S1_BLOCKS, 256, 0, stream>>>(adj, bucket_cnt, staging,
                                                     X, fcwT, fc_b, F, Xb);
    sort2_kernel<<<NBKT, 256, 0, stream>>>(bucket_cnt, staging, degp, elLo, elHi);
    aggregate_all_kernel<<<AGG_PHASE_BLOCKS * 2, 256, 0, stream>>>(F, degp, elLo, elHi,
                                                                   aggLo, aggHi);
    gemm2_kernel<<<GEMM_MT, 256, 0, stream>>>(Xb, aggLo, aggHi, WT, outp);
}

// Round 18
// 243.271 us; speedup vs baseline: 1.1071x; 1.0250x over previous
//
#include <hip/hip_runtime.h>
#include <hip/hip_bf16.h>

#define N_NODES 50000
#define N_EDGES 800000
#define D_IN 128
#define D_HID 512
#define D_OUT 128
#define CAT_DIM 640   // D_IN + D_HID
#define CAPH 32       // per-half capacity (Poisson(8): P(>32) ~ 3e-11)
#define HALF 25000    // trg-phase split point

typedef __attribute__((ext_vector_type(8))) short short8;
typedef __attribute__((ext_vector_type(4))) float floatx4;
typedef __attribute__((ext_vector_type(8))) unsigned short ushortx8;

__device__ __forceinline__ unsigned short f2bf(float f) {
    unsigned u = __float_as_uint(f);
    unsigned r = u + 0x7fffu + ((u >> 16) & 1u);   // RNE
    return (unsigned short)(r >> 16);
}

// convert 8 consecutive fp32 -> 8 bf16 (same bits as a pre-cast pass)
__device__ __forceinline__ void cvt8(const float* __restrict__ src, unsigned short* o) {
    float4 v0 = *(const float4*)src;
    float4 v1 = *(const float4*)(src + 4);
    o[0] = f2bf(v0.x); o[1] = f2bf(v0.y); o[2] = f2bf(v0.z); o[3] = f2bf(v0.w);
    o[4] = f2bf(v1.x); o[5] = f2bf(v1.y); o[6] = f2bf(v1.z); o[7] = f2bf(v1.w);
}

// ================= edge binning parameters =================================

#define NBKT 196         // ceil(50000/256)
#define BKT_SHIFT 8
#define CAPB 6144        // staging capacity/bucket (mean 4082, +32 sigma)
#define P1_CHUNK 4096
#define P1_BLOCKS 196    // ceil(800000/4096)

// ================= k0: weight transposes + bucket_cnt zero =================

#define K0_FCW_BLOCKS 256   // 128*512 / 256
#define K0_WT_BLOCKS  320   // 640*128 / 256
#define K0_BLOCKS (K0_FCW_BLOCKS + K0_WT_BLOCKS + 1)

__global__ __launch_bounds__(256)
void prep_w_kernel(const float* __restrict__ fcW, const float* __restrict__ Wm,
                   unsigned short* __restrict__ fcwT, unsigned short* __restrict__ WT,
                   int* __restrict__ bucket_cnt) {
    int b = blockIdx.x, tid = threadIdx.x;
    if (b < K0_FCW_BLOCKS) {
        int idx = b * 256 + tid;               // 128*512
        int k = idx >> 9;
        int n = idx & (D_HID - 1);
        fcwT[n * D_IN + k] = f2bf(fcW[idx]);
        return;
    }
    b -= K0_FCW_BLOCKS;
    if (b < K0_WT_BLOCKS) {
        int idx = b * 256 + tid;               // 640*128
        int k = idx >> 7;
        int n = idx & (D_OUT - 1);
        WT[n * CAT_DIM + k] = f2bf(Wm[idx]);
        return;
    }
    if (tid < NBKT) bucket_cnt[tid] = 0;
}

// ================= k1: binning ∥ GEMM1 (R13 exact + Xb emit) ===============
// LDS 35840 B -> 4 blocks/CU; grid 978 <= 1024 resident -> single round.

#define S1_G1_BLOCKS 782    // ceil(50000/64)
#define S1_BLOCKS (P1_BLOCKS + S1_G1_BLOCKS)
#define G1_PAD 8
#define SM1_BYTES (64 * (D_IN + G1_PAD) * 2 + 128 * (64 + G1_PAD) * 2)   // 35840

__global__ __launch_bounds__(256)
void sort_gemm1_kernel(const int* __restrict__ adj,
                       int* __restrict__ bucket_cnt, uint2* __restrict__ staging,
                       const float* __restrict__ X,
                       const unsigned short* __restrict__ fcwT,
                       const float* __restrict__ fcb,
                       unsigned short* __restrict__ F,
                       unsigned short* __restrict__ Xb) {
    __shared__ alignas(16) char smem[SM1_BYTES];
    int b = blockIdx.x, tid = threadIdx.x;
    if (b < P1_BLOCKS) {
        uint2* les = (uint2*)smem;                     // 32 KB
        int* cnt   = (int*)(smem + P1_CHUNK * 8);      // 196 ints
        int* woff  = cnt + NBKT;
        for (int i = tid; i < NBKT; i += 256) cnt[i] = 0;
        // per-wave dtype detect: int64 iff high dwords of first 64 ids all zero
        int v = adj[2 * (tid & 63) + 1];
        int s = (__ballot(v != 0) == 0ULL) ? 2 : 1;
        __syncthreads();
        int e0 = b * P1_CHUNK;
        int ne = N_EDGES - e0; if (ne > P1_CHUNK) ne = P1_CHUNK;
        for (int j = tid; j < ne; j += 256) {
            int e = e0 + j;
            int src, trg;
            if (s == 2) { src = adj[2 * (size_t)e]; trg = adj[2 * ((size_t)N_EDGES + e)]; }
            else        { src = adj[e];             trg = adj[N_EDGES + e]; }
            les[j] = make_uint2((unsigned)src, (unsigned)trg);
            atomicAdd(&cnt[src >> BKT_SHIFT], 1);           // LDS atomic
        }
        __syncthreads();
        for (int i = tid; i < NBKT; i += 256)
            woff[i] = atomicAdd(&bucket_cnt[i], cnt[i]);    // 196 global atomics/block
        __syncthreads();
        for (int j = tid; j < ne; j += 256) {
            uint2 et = les[j];
            int bk = (int)(et.x >> BKT_SHIFT);
            int pos = atomicAdd(&woff[bk], 1);              // LDS atomic
            if (pos < CAPB) staging[(size_t)bk * CAPB + pos] = et;
        }
        return;
    }
    b -= P1_BLOCKS;
    {
        typedef unsigned short RowA[D_IN + G1_PAD];
        typedef unsigned short RowB[64 + G1_PAD];
        RowA* As = (RowA*)smem;
        RowB* Bs = (RowB*)(smem + 64 * (D_IN + G1_PAD) * 2);
        int lane = tid & 63, w = tid >> 6;
        int bm = b * 64;
        {   // stage A once: 4 passes x (16 rows x 128 cols), fp32 -> bf16; emit Xb
            int r = tid >> 4;
            int c = (tid & 15) * 8;
            #pragma unroll
            for (int p = 0; p < 4; ++p) {
                int row = r + p * 16;
                int gr = bm + row;
                unsigned short o[8] = {0, 0, 0, 0, 0, 0, 0, 0};
                if (gr < N_NODES) {
                    cvt8(X + (size_t)gr * D_IN + c, o);
                    *(uint4*)(Xb + (size_t)gr * D_IN + c) = *(const uint4*)o;
                }
                *(uint4*)(&As[row][c]) = *(const uint4*)o;
            }
        }
        int wm = (w >> 1) * 32, wn = (w & 1) * 64;
        int q = lane >> 4, l16 = lane & 15;
        int rb = tid >> 1;            // B row 0..127
        int cb = (tid & 1) * 8;       // B col base; passes +0,+16,+32,+48
        for (int nc = 0; nc < 4; ++nc) {
            floatx4 acc[2][4] = {};
            #pragma unroll
            for (int kh = 0; kh < 2; ++kh) {
                {   // stage B: fcwT rows [nc*128, +128), cols [kh*64, +64)
                    const unsigned short* bp = fcwT + (size_t)(nc * 128 + rb) * D_IN + kh * 64 + cb;
                    #pragma unroll
                    for (int p = 0; p < 4; ++p)
                        *(uint4*)(&Bs[rb][cb + p * 16]) = *(const uint4*)(bp + p * 16);
                }
                __syncthreads();
                #pragma unroll
                for (int ks = 0; ks < 2; ++ks) {
                    short8 af[2], bf[4];
                    #pragma unroll
                    for (int mi = 0; mi < 2; ++mi)
                        af[mi] = *(const short8*)(&As[wm + mi * 16 + l16][kh * 64 + ks * 32 + q * 8]);
                    #pragma unroll
                    for (int ni = 0; ni < 4; ++ni)
                        bf[ni] = *(const short8*)(&Bs[wn + ni * 16 + l16][ks * 32 + q * 8]);
                    #pragma unroll
                    for (int mi = 0; mi < 2; ++mi)
                        #pragma unroll
                        for (int ni = 0; ni < 4; ++ni)
                            acc[mi][ni] = __builtin_amdgcn_mfma_f32_16x16x32_bf16(af[mi], bf[ni], acc[mi][ni], 0, 0, 0);
                }
                __syncthreads();   // protect Bs before restage
            }
            #pragma unroll
            for (int mi = 0; mi < 2; ++mi)
                #pragma unroll
                for (int ni = 0; ni < 4; ++ni)
                    #pragma unroll
                    for (int r = 0; r < 4; ++r) {
                        int row = bm + wm + mi * 16 + q * 4 + r;
                        int col = nc * 128 + wn + ni * 16 + l16;
                        if (row < N_NODES) {
                            float v = fmaxf(acc[mi][ni][r] + fcb[col], 0.0f);
                            F[(size_t)row * D_HID + col] = f2bf(v);
                        }
                    }
        }
    }
}

// ================= k2: pass-2 scatter into phase-split el arrays ===========

__global__ __launch_bounds__(256)
void sort2_kernel(const int* __restrict__ bucket_cnt, const uint2* __restrict__ staging,
                  int* __restrict__ degp,
                  unsigned short* __restrict__ elLo, unsigned short* __restrict__ elHi) {
    __shared__ int lo[256], hi[256];
    int bk = blockIdx.x, tid = threadIdx.x;
    lo[tid] = 0; hi[tid] = 0;
    __syncthreads();
    int n = bucket_cnt[bk]; if (n > CAPB) n = CAPB;
    int base = bk << BKT_SHIFT;
    const uint2* st = staging + (size_t)bk * CAPB;
    for (int i = tid; i < n; i += 256) {
        uint2 et = st[i];
        int r = (int)et.x - base;
        int t = (int)et.y;
        if (t < HALF) {
            int p = atomicAdd(&lo[r], 1);
            if (p < CAPH) elLo[(size_t)(base + r) * CAPH + p] = (unsigned short)t;
        } else {
            int p = atomicAdd(&hi[r], 1);
            if (p < CAPH) elHi[(size_t)(base + r) * CAPH + p] = (unsigned short)t;
        }
    }
    __syncthreads();
    int src = base + tid;
    if (src < N_NODES) degp[src] = lo[tid] | (hi[tid] << 16);
}

// ================= merged aggregate: packed u16 integer max ================
// R17 established this kernel is at the compulsory FETCH floor (104 MB) with
// VALUBusy 49% -- now ARITHMETIC-bound: ~22 VALU ops/edge-visit for unpack +
// fmaxf + repack. Fix: F values are post-ReLU bf16 (>= 0, no NaN) so bit
// order = value order -> accumulate with PACKED U16 INTEGER MAX directly on
// the loaded bits (v_pk_max_u16 x4 per edge, no unpack, no repack). Result
// bits identical to the fmaxf path. Geometry/caching frozen (R17 form).

#define AGG_CHUNKS 1563   // ceil(50000/32)
#define AGG_PHASE_BLOCKS (AGG_CHUNKS * 8)

__global__ __launch_bounds__(256)
void aggregate_all_kernel(const unsigned short* __restrict__ F,
                          const int* __restrict__ degp,
                          const unsigned short* __restrict__ elLo,
                          const unsigned short* __restrict__ elHi,
                          unsigned short* __restrict__ aggLo,
                          unsigned short* __restrict__ aggHi) {
    int tid = threadIdx.x;
    int H = blockIdx.x >= AGG_PHASE_BLOCKS;
    int pb = blockIdx.x - H * AGG_PHASE_BLOCKS;
    int s = pb & 7;                    // column slice -> XCD (default %8 map)
    int chunk = pb >> 3;
    int n = chunk * 32 + (tid >> 3);   // node owned by this 8-lane group
    int ch = tid & 7;                  // 16B chunk within the 128B slice
    if (n >= N_NODES) return;
    int dp = degp[n];
    int d = H ? (dp >> 16) : (dp & 0xffff);
    d = d < CAPH ? d : CAPH;
    const unsigned short* el = H ? elHi : elLo;
    unsigned short* agg = H ? aggHi : aggLo;
    const unsigned short* Fs = F + s * 64 + ch * 8;
    const unsigned short* ep = el + (size_t)n * CAPH;
    ushortx8 acc = {};                 // 0x0000 == bf16 +0; all F >= 0
    #pragma unroll 2
    for (int i = 0; i < d; ++i) {
        int t = ep[i];
        ushortx8 p = *(const ushortx8*)(Fs + (size_t)t * D_HID);
        acc = __builtin_elementwise_max(acc, p);   // v_pk_max_u16: exact fmax for non-neg bf16
    }
    *(ushortx8*)(agg + (size_t)n * D_HID + s * 64 + ch * 8) = acc;
}

// ================= GEMM2: A = [Xb bf16 | max(aggLo,aggHi)], B = WT =========
// BM=64, BN=128 (full D_OUT), BK=64, 10 K-steps. LDS 27648 B. The per-u16
// unsigned max IS the float max here (non-negative bf16).

#define GPAD 8
#define GEMM_MT 782   // ceil(50000/64)

__global__ __launch_bounds__(256)
void gemm2_kernel(const unsigned short* __restrict__ Xb,
                  const unsigned short* __restrict__ aggLo,
                  const unsigned short* __restrict__ aggHi,
                  const unsigned short* __restrict__ WT,
                  float* __restrict__ out) {
    __shared__ unsigned short As[64][64 + GPAD];
    __shared__ unsigned short Bs[128][64 + GPAD];
    int tid = threadIdx.x;
    int lane = tid & 63, w = tid >> 6;
    int wm = (w >> 1) * 32, wn = (w & 1) * 64;
    int q = lane >> 4, l16 = lane & 15;
    int bm = blockIdx.x * 64;
    floatx4 acc[2][4] = {};
    int ra = tid >> 2;            // A row 0..63
    int ca = (tid & 3) * 8;       // A col base; passes +0,+32
    int rb = tid >> 1;            // B row 0..127
    int cb = (tid & 1) * 8;       // B col base; passes +0,+16,+32,+48

    for (int k0 = 0; k0 < CAT_DIM; k0 += 64) {
        {
            int gr = bm + ra;
            #pragma unroll
            for (int p = 0; p < 2; ++p) {
                int col = k0 + ca + p * 32;
                unsigned short o[8] = {0, 0, 0, 0, 0, 0, 0, 0};
                if (gr < N_NODES) {
                    if (col < D_IN) {
                        *(uint4*)o = *(const uint4*)(Xb + (size_t)gr * D_IN + col);
                    } else {
                        ushortx8 vl = *(const ushortx8*)(aggLo + (size_t)gr * D_HID + (col - D_IN));
                        ushortx8 vh = *(const ushortx8*)(aggHi + (size_t)gr * D_HID + (col - D_IN));
                        ushortx8 vm = __builtin_elementwise_max(vl, vh);   // exact fmax (non-neg bf16)
                        *(ushortx8*)o = vm;
                    }
                }
                *(uint4*)(&As[ra][ca + p * 32]) = *(const uint4*)o;
            }
        }
        {
            const unsigned short* bp = WT + (size_t)rb * CAT_DIM + k0 + cb;
            #pragma unroll
            for (int p = 0; p < 4; ++p)
                *(uint4*)(&Bs[rb][cb + p * 16]) = *(const uint4*)(bp + p * 16);
        }
        __syncthreads();
        #pragma unroll
        for (int ks = 0; ks < 2; ++ks) {
            short8 af[2], bf[4];
            #pragma unroll
            for (int mi = 0; mi < 2; ++mi)
                af[mi] = *(const short8*)(&As[wm + mi * 16 + l16][ks * 32 + q * 8]);
            #pragma unroll
            for (int ni = 0; ni < 4; ++ni)
                bf[ni] = *(const short8*)(&Bs[wn + ni * 16 + l16][ks * 32 + q * 8]);
            #pragma unroll
            for (int mi = 0; mi < 2; ++mi)
                #pragma unroll
                for (int ni = 0; ni < 4; ++ni)
                    acc[mi][ni] = __builtin_amdgcn_mfma_f32_16x16x32_bf16(af[mi], bf[ni], acc[mi][ni], 0, 0, 0);
        }
        __syncthreads();
    }

    #pragma unroll
    for (int mi = 0; mi < 2; ++mi)
        #pragma unroll
        for (int ni = 0; ni < 4; ++ni)
            #pragma unroll
            for (int r = 0; r < 4; ++r) {
                int row = bm + wm + mi * 16 + q * 4 + r;
                int col = wn + ni * 16 + l16;
                if (row < N_NODES)
                    out[(size_t)row * D_OUT + col] = acc[mi][ni][r];
            }
}

// ================= host launch =============================================

extern "C" void kernel_launch(void* const* d_in, const int* in_sizes, int n_in,
                              void* d_out, int out_size, void* d_ws, size_t ws_size,
                              hipStream_t stream) {
    const float* X    = (const float*)d_in[0];
    const float* fc_w = (const float*)d_in[1];
    const float* fc_b = (const float*)d_in[2];
    const float* Wm   = (const float*)d_in[3];
    const int*   adj  = (const int*)d_in[4];
    float* outp = (float*)d_out;

    char* ws = (char*)d_ws;
    size_t off = 0;
    auto alloc = [&](size_t bytes) -> void* {
        void* p = ws + off;
        off = (off + bytes + 255) & ~(size_t)255;
        return p;
    };
    unsigned short* aggLo  = (unsigned short*)alloc((size_t)N_NODES * D_HID * 2);
    unsigned short* aggHi  = (unsigned short*)alloc((size_t)N_NODES * D_HID * 2);
    unsigned short* F      = (unsigned short*)alloc((size_t)N_NODES * D_HID * 2);
    unsigned short* Xb     = (unsigned short*)alloc((size_t)N_NODES * D_IN * 2);
    unsigned short* fcwT   = (unsigned short*)alloc((size_t)D_HID * D_IN * 2);
    unsigned short* WT     = (unsigned short*)alloc((size_t)D_OUT * CAT_DIM * 2);
    int* degp      = (int*)alloc((size_t)N_NODES * 4);
    unsigned short* elLo = (unsigned short*)alloc((size_t)N_NODES * CAPH * 2);
    unsigned short* elHi = (unsigned short*)alloc((size_t)N_NODES * CAPH * 2);
    int* bucket_cnt = (int*)alloc((size_t)NBKT * 4);
    uint2* staging  = (uint2*)alloc((size_t)NBKT * CAPB * 8);

    prep_w_kernel<<<K0_BLOCKS, 256, 0, stream>>>(fc_w, Wm, fcwT, WT, bucket_cnt);
    sort_gemm1_kernel<<<S1_BLOCKS, 256, 0, stream>>>(adj, bucket_cnt, staging,
                                                     X, fcwT, fc_b, F, Xb);
    sort2_kernel<<<NBKT, 256, 0, stream>>>(bucket_cnt, staging, degp, elLo, elHi);
    aggregate_all_kernel<<<AGG_PHASE_BLOCKS * 2, 256, 0, stream>>>(F, degp, elLo, elHi,
                                                                   aggLo, aggHi);
    gemm2_kernel<<<GEMM_MT, 256, 0, stream>>>(Xb, aggLo, aggHi, WT, outp);
}